// Round 1
// baseline (698.841 us; speedup 1.0000x reference)
//
#include <hip/hip_runtime.h>
#include <math.h>

#define LEAKY(v) ((v) > 0.f ? (v) : 0.01f * (v))

// ------------------------------------------------------------------ prep ----
__device__ __forceinline__ void cmm2(const float* Ar, const float* Ai,
                                     const float* Br, const float* Bi,
                                     float* Cr, float* Ci) {
#pragma unroll
  for (int r = 0; r < 2; r++)
#pragma unroll
    for (int c = 0; c < 2; c++) {
      float xr = 0.f, xi = 0.f;
#pragma unroll
      for (int k = 0; k < 2; k++) {
        float ar = Ar[r*2+k], ai = Ai[r*2+k];
        float br = Br[k*2+c], bi = Bi[k*2+c];
        xr += ar*br - ai*bi;
        xi += ar*bi + ai*br;
      }
      Cr[r*2+c] = xr; Ci[r*2+c] = xi;
    }
}

// Computes the 60 fused 2x2 gate matrices G = U3 @ RZ @ RY @ RX and zeroes the
// 1280 floats of BN-statistics accumulators (ws is poisoned before each call).
__global__ __launch_bounds__(256) void prep_k(const float* __restrict__ qw,
                                              float* __restrict__ gates,
                                              float* __restrict__ stats) {
  int t = threadIdx.x;
  for (int i = t; i < 1280; i += 256) stats[i] = 0.f;
  if (t < 60) {
    float a = qw[t*3+0], b = qw[t*3+1], c = qw[t*3+2];
    float ca = cosf(0.5f*a), sa = sinf(0.5f*a);
    float cb = cosf(0.5f*b), sb = sinf(0.5f*b);
    float RXr[4] = {ca, 0.f, 0.f, ca};
    float RXi[4] = {0.f, -sa, -sa, 0.f};
    float RYr[4] = {cb, -sb, sb, cb};
    float RYi[4] = {0.f, 0.f, 0.f, 0.f};
    float hc = 0.5f*c;
    float RZr[4] = {cosf(hc), 0.f, 0.f, cosf(hc)};
    float RZi[4] = {-sinf(hc), 0.f, 0.f, sinf(hc)};
    float epr = cosf(b), epi = sinf(b);   // e^{ib}
    float edr = cosf(c), edi = sinf(c);   // e^{ic}
    float eer = epr*edr - epi*edi, eei = epr*edi + epi*edr;
    float U3r[4] = {ca, -edr*sa, epr*sa, eer*ca};
    float U3i[4] = {0.f, -edi*sa, epi*sa, eei*ca};
    float T1r[4],T1i[4],T2r[4],T2i[4],Gr[4],Gi[4];
    cmm2(RYr,RYi, RXr,RXi, T1r,T1i);
    cmm2(RZr,RZi, T1r,T1i, T2r,T2i);
    cmm2(U3r,U3i, T2r,T2i, Gr,Gi);
#pragma unroll
    for (int m = 0; m < 4; m++) {
      gates[t*8 + 2*m]     = Gr[m];
      gates[t*8 + 2*m + 1] = Gi[m];
    }
  }
}

// ------------------------------------------------------------------ gemm ----
// C[r][c] = sum_k A[r][k] * W[c][k] + bias[c].  64x64 tiles, 256 threads,
// 4x4 micro-tile per thread.  Handles arbitrary K (zero-padded chunks).
__global__ __launch_bounds__(256) void gemm_k(const float* __restrict__ A,
                                              const float* __restrict__ W,
                                              const float* __restrict__ bias,
                                              float* __restrict__ C,
                                              int N, int K) {
  __shared__ float As[64][65];
  __shared__ float Bs[64][65];
  const int r0 = blockIdx.x * 64;
  const int c0 = blockIdx.y * 64;
  const int tid = threadIdx.x;
  const int ty = tid >> 4, tx = tid & 15;
  float acc[4][4] = {};
  for (int kc = 0; kc < K; kc += 64) {
#pragma unroll
    for (int i = 0; i < 16; i++) {
      int t = tid + 256*i;
      int lr = t >> 6, lk = t & 63;
      float av = 0.f, wv = 0.f;
      if (kc + lk < K) {
        av = A[(size_t)(r0+lr)*K + kc + lk];
        if (c0 + lr < N) wv = W[(size_t)(c0+lr)*K + kc + lk];
      }
      As[lr][lk] = av;
      Bs[lr][lk] = wv;
    }
    __syncthreads();
#pragma unroll 16
    for (int kk = 0; kk < 64; kk++) {
      float ar[4], wr[4];
#pragma unroll
      for (int i = 0; i < 4; i++) ar[i] = As[ty*4+i][kk];
#pragma unroll
      for (int j = 0; j < 4; j++) wr[j] = Bs[tx*4+j][kk];
#pragma unroll
      for (int i = 0; i < 4; i++)
#pragma unroll
        for (int j = 0; j < 4; j++)
          acc[i][j] += ar[i]*wr[j];
    }
    __syncthreads();
  }
#pragma unroll
  for (int i = 0; i < 4; i++) {
    int r = r0 + ty*4 + i;
#pragma unroll
    for (int j = 0; j < 4; j++) {
      int c = c0 + tx*4 + j;
      if (c < N) C[(size_t)r*N + c] = acc[i][j] + bias[c];
    }
  }
}

// ------------------------------------------------------- column statistics ----
// stats[2c] += sum, stats[2c+1] += sumsq over 256 rows per block.y section.
__global__ __launch_bounds__(256) void colstats_k(const float* __restrict__ Z,
                                                  float* __restrict__ stats,
                                                  int N) {
  const int c0 = blockIdx.x * 64;
  const int sec = blockIdx.y;
  const int cc = threadIdx.x & 63, rg = threadIdx.x >> 6;
  float s = 0.f, s2 = 0.f;
  for (int r = sec*256 + rg; r < sec*256 + 256; r += 4) {
    float v = Z[(size_t)r*N + c0 + cc];
    s += v; s2 += v*v;
  }
  __shared__ float sh0[256];
  __shared__ float sh1[256];
  sh0[threadIdx.x] = s; sh1[threadIdx.x] = s2;
  __syncthreads();
  if (rg == 0) {
    s  = sh0[cc] + sh0[cc+64] + sh0[cc+128] + sh0[cc+192];
    s2 = sh1[cc] + sh1[cc+64] + sh1[cc+128] + sh1[cc+192];
    atomicAdd(&stats[2*(c0+cc)], s);
    atomicAdd(&stats[2*(c0+cc)+1], s2);
  }
}

// ----------------------------------------------------------- BN + leaky ----
// out[i] = leaky(g*(z-mean)*rsqrt(var+eps)+be) (+ addscale*addsrc[r*addld+c])
// In-place safe (pure elementwise).
__global__ __launch_bounds__(256) void bn_k(const float* __restrict__ Z,
                                            const float* __restrict__ stats,
                                            const float* __restrict__ g,
                                            const float* __restrict__ be,
                                            const float* __restrict__ addsrc,
                                            float addscale, int addld,
                                            float* __restrict__ out, int N) {
  int i = blockIdx.x * 256 + threadIdx.x;
  int c = i % N, r = i / N;
  float mean = stats[2*c] * (1.f/4096.f);
  float var  = stats[2*c+1] * (1.f/4096.f) - mean*mean;
  float v = g[c] * (Z[i] - mean) * rsqrtf(var + 1e-5f) + be[c];
  v = LEAKY(v);
  if (addsrc) v += addscale * addsrc[(size_t)r*addld + c];
  out[i] = v;
}

// ----------------------------------------------------------- quantum sim ----
// One block per batch row. State (4096 complex) lives in registers: 16 amps
// per thread. LDS (XOR-swizzled) used only for the 3 re-localization passes
// per layer + 1 CNOT-chain gather (CNOT chain = GF(2)-linear bit permutation).
#define SWZ(i) ((i) ^ (((i) >> 4) & 15))

template<int BETA>
__device__ __forceinline__ void apply_bit(float2* a, const float* __restrict__ g) {
  float g00r=g[0], g00i=g[1], g01r=g[2], g01i=g[3];
  float g10r=g[4], g10i=g[5], g11r=g[6], g11i=g[7];
#pragma unroll
  for (int m = 0; m < 8; m++) {
    int l0 = ((m >> BETA) << (BETA+1)) | (m & ((1<<BETA)-1));
    int l1 = l0 | (1 << BETA);
    float2 A = a[l0], Bv = a[l1];
    float n0r = g00r*A.x - g00i*A.y + g01r*Bv.x - g01i*Bv.y;
    float n0i = g00r*A.y + g00i*A.x + g01r*Bv.y + g01i*Bv.x;
    float n1r = g10r*A.x - g10i*A.y + g11r*Bv.x - g11i*Bv.y;
    float n1i = g10r*A.y + g10i*A.x + g11r*Bv.y + g11i*Bv.x;
    a[l0] = make_float2(n0r, n0i);
    a[l1] = make_float2(n1r, n1i);
  }
}

// 4 gates on the 4 local bits; qubit qb+k sits on local bit 3-k.
__device__ __forceinline__ void apply4(float2* a, const float* __restrict__ gl, int qb) {
  apply_bit<3>(a, gl + (qb+0)*8);
  apply_bit<2>(a, gl + (qb+1)*8);
  apply_bit<1>(a, gl + (qb+2)*8);
  apply_bit<0>(a, gl + (qb+3)*8);
}

__global__ __launch_bounds__(256) void quantum_k(const float* __restrict__ zpre,
                                                 const float* __restrict__ gates,
                                                 float* __restrict__ qout) {
  __shared__ float2 st[4096];
  __shared__ float trig[24];
  __shared__ float red[4][18];
  const int b = blockIdx.x, tid = threadIdx.x;
  if (tid < 12) {
    float xp = tanhf(zpre[b*12 + tid]);
    float h = xp * 1.57079632679489662f;   // pi/2
    trig[tid] = cosf(h);
    trig[12 + tid] = sinf(h);
  }
  __syncthreads();
  // Product-state init, layout A: idx = tid<<4 | l (qubit q <-> idx bit 11-q).
  float2 a[16];
  {
    float cs[12], sn[12];
#pragma unroll
    for (int q = 0; q < 12; q++) { cs[q] = trig[q]; sn[q] = trig[12+q]; }
    float pre = 1.f;
#pragma unroll
    for (int q = 0; q < 8; q++) pre *= ((tid >> (7-q)) & 1) ? sn[q] : cs[q];
#pragma unroll
    for (int l = 0; l < 16; l++) {
      float v = pre;
      v *= (l & 8) ? sn[8]  : cs[8];
      v *= (l & 4) ? sn[9]  : cs[9];
      v *= (l & 2) ? sn[10] : cs[10];
      v *= (l & 1) ? sn[11] : cs[11];
      a[l] = make_float2(v, 0.f);
    }
  }
  const int hiB = ((tid >> 4) << 8) | (tid & 15);  // layout B: l in idx bits 7..4
  for (int layer = 0; layer < 5; layer++) {
    const float* gl = gates + layer * 96;
    apply4(a, gl, 8);                               // qubits 8..11 (local, layout A)
#pragma unroll
    for (int l = 0; l < 16; l++) st[SWZ((tid << 4) | l)] = a[l];
    __syncthreads();
#pragma unroll
    for (int l = 0; l < 16; l++) a[l] = st[SWZ(hiB | (l << 4))];
    apply4(a, gl, 4);                               // qubits 4..7
#pragma unroll
    for (int l = 0; l < 16; l++) st[SWZ(hiB | (l << 4))] = a[l];
    __syncthreads();
#pragma unroll
    for (int l = 0; l < 16; l++) a[l] = st[SWZ((l << 8) | tid)];
    apply4(a, gl, 0);                               // qubits 0..3
#pragma unroll
    for (int l = 0; l < 16; l++) st[SWZ((l << 8) | tid)] = a[l];
    __syncthreads();
    // CNOT chain folded into a single linear gather back to layout A:
    // new_amp[i] = old_amp[Linv(i)].
    if ((layer & 1) == 0) {
#pragma unroll
      for (int l = 0; l < 16; l++) {
        int i = (tid << 4) | l;
        int s = i ^ ((i >> 1) & 0x7FF) ^ ((i & 1) ? 0xC00 : 0);
        a[l] = st[SWZ(s)];
      }
    } else {
#pragma unroll
      for (int l = 0; l < 16; l++) {
        int i = (tid << 4) | l;
        int hi = i & 0xAAA;
        int s = (i & 0x555) | ((hi ^ (hi << 6)) & 0xA80) | ((hi >> 6) & 0x2A);
        a[l] = st[SWZ(s)];
      }
    }
    __syncthreads();
  }
  // ---- measurement: 12 Z expectations + 6 X-type pair sums ----
  float pl[16], tot = 0.f;
#pragma unroll
  for (int l = 0; l < 16; l++) { pl[l] = a[l].x*a[l].x + a[l].y*a[l].y; tot += pl[l]; }
  float part[18];
#pragma unroll
  for (int q = 0; q < 8; q++) part[q] = ((tid >> (7-q)) & 1) ? -tot : tot;
#pragma unroll
  for (int q = 8; q < 12; q++) {
    int bit = 11 - q;
    float s = 0.f;
#pragma unroll
    for (int l = 0; l < 16; l++) s += ((l >> bit) & 1) ? -pl[l] : pl[l];
    part[q] = s;
  }
#pragma unroll
  for (int l = 0; l < 16; l++) st[SWZ((tid << 4) | l)] = a[l];
  __syncthreads();
#pragma unroll
  for (int q = 0; q < 6; q++) {
    int bt = 7 - q;                 // qubit q <-> idx bit 11-q = tid bit 7-q
    float s = 0.f;
    if (((tid >> bt) & 1) == 0) {
      int tid2 = tid | (1 << bt);
#pragma unroll
      for (int l = 0; l < 16; l++) {
        float2 bb = st[SWZ((tid2 << 4) | l)];
        s += a[l].x*bb.x + a[l].y*bb.y;   // Re(conj(a0)*a1)
      }
    }
    part[12+q] = 2.f * s;
  }
#pragma unroll
  for (int j = 0; j < 18; j++) {
    float v = part[j];
#pragma unroll
    for (int m = 1; m < 64; m <<= 1) v += __shfl_xor(v, m);
    if ((tid & 63) == 0) red[tid >> 6][j] = v;
  }
  __syncthreads();
  if (tid < 18) qout[b*18 + tid] = red[0][tid] + red[1][tid] + red[2][tid] + red[3][tid];
}

// ---------------------------------------------------------------- final ----
// out[r] = leaky(p2_r @ Wo1^T + bo1) @ Wo2^T + bo2.  32 lanes per row.
__global__ __launch_bounds__(256) void final_k(const float* __restrict__ P2,
                                               const float* __restrict__ Wo1,
                                               const float* __restrict__ bo1,
                                               const float* __restrict__ Wo2,
                                               const float* __restrict__ bo2,
                                               float* __restrict__ out) {
  int row = blockIdx.x*8 + (threadIdx.x >> 5);
  int o = threadIdx.x & 31;
  float acc = 0.f;
#pragma unroll 8
  for (int k = 0; k < 64; k++) acc += P2[(size_t)row*64 + k] * Wo1[o*64 + k];
  float h = acc + bo1[o];
  h = LEAKY(h);
  float v = h * Wo2[o];
#pragma unroll
  for (int m = 1; m < 32; m <<= 1) v += __shfl_xor(v, m);
  if (o == 0) out[row] = v + bo2[0];
}

// --------------------------------------------------------------- launch ----
extern "C" void kernel_launch(void* const* d_in, const int* in_sizes, int n_in,
                              void* d_out, int out_size, void* d_ws, size_t ws_size,
                              hipStream_t stream) {
  (void)in_sizes; (void)n_in; (void)out_size; (void)ws_size;
  const float* x   = (const float*)d_in[0];
  const float* Wsk = (const float*)d_in[1];
  const float* bs  = (const float*)d_in[2];
  const float* W1  = (const float*)d_in[3];
  const float* b1  = (const float*)d_in[4];
  const float* g1  = (const float*)d_in[5];
  const float* be1 = (const float*)d_in[6];
  const float* W2  = (const float*)d_in[7];
  const float* b2  = (const float*)d_in[8];
  const float* g2  = (const float*)d_in[9];
  const float* be2 = (const float*)d_in[10];
  const float* W3  = (const float*)d_in[11];
  const float* b3  = (const float*)d_in[12];
  const float* g3  = (const float*)d_in[13];
  const float* be3 = (const float*)d_in[14];
  const float* Wp  = (const float*)d_in[15];
  const float* bp  = (const float*)d_in[16];
  const float* qw  = (const float*)d_in[17];
  const float* Wq1 = (const float*)d_in[18];
  const float* bq1 = (const float*)d_in[19];
  const float* gq1 = (const float*)d_in[20];
  const float* beq1= (const float*)d_in[21];
  const float* Wq2 = (const float*)d_in[22];
  const float* bq2 = (const float*)d_in[23];
  const float* gq2 = (const float*)d_in[24];
  const float* beq2= (const float*)d_in[25];
  const float* Wo1 = (const float*)d_in[26];
  const float* bo1 = (const float*)d_in[27];
  const float* Wo2 = (const float*)d_in[28];
  const float* bo2 = (const float*)d_in[29];
  float* out = (float*)d_out;
  float* ws = (float*)d_ws;

  // workspace layout (floats); buffers are live-range aliased (~10 MB total)
  float* GATES = ws;                       // 480
  float* ST1 = ws + 480;                   // 512
  float* ST2 = ST1 + 512;                  // 256
  float* ST3 = ST2 + 256;                  // 128
  float* SQ1 = ST3 + 128;                  // 256
  float* SQ2 = SQ1 + 256;                  // 128 (stats end at ws+1760)
  float* SKIP = ws + 2048;                 // 4096*128
  float* BUF1 = SKIP + 4096*128;           // 4096*256  (z1 -> x1, alive to x3-bn)
  float* BUF2 = BUF1 + 4096*256;           // 4096*128  (z2/x2, later zq1/p1)
  float* BUF3 = BUF2 + 4096*128;           // 4096*64   (z3/x3, later zq2/p2)
  float* ZP   = BUF3 + 4096*64;            // 4096*12
  float* QOUT = ZP + 4096*12;              // 4096*18

  dim3 blk(256);
  prep_k<<<1, blk, 0, stream>>>(qw, GATES, ST1);
  gemm_k<<<dim3(64,2), blk, 0, stream>>>(x, Wsk, bs, SKIP, 128, 64);
  gemm_k<<<dim3(64,4), blk, 0, stream>>>(x, W1, b1, BUF1, 256, 64);
  colstats_k<<<dim3(4,16), blk, 0, stream>>>(BUF1, ST1, 256);
  bn_k<<<dim3(4096*256/256), blk, 0, stream>>>(BUF1, ST1, g1, be1, nullptr, 0.f, 0, BUF1, 256);
  gemm_k<<<dim3(64,2), blk, 0, stream>>>(BUF1, W2, b2, BUF2, 128, 256);
  colstats_k<<<dim3(2,16), blk, 0, stream>>>(BUF2, ST2, 128);
  bn_k<<<dim3(4096*128/256), blk, 0, stream>>>(BUF2, ST2, g2, be2, nullptr, 0.f, 0, BUF2, 128);
  gemm_k<<<dim3(64,1), blk, 0, stream>>>(BUF2, W3, b3, BUF3, 64, 128);
  colstats_k<<<dim3(1,16), blk, 0, stream>>>(BUF3, ST3, 64);
  bn_k<<<dim3(4096*64/256), blk, 0, stream>>>(BUF3, ST3, g3, be3, BUF1, 0.1f, 256, BUF3, 64);
  gemm_k<<<dim3(64,1), blk, 0, stream>>>(BUF3, Wp, bp, ZP, 12, 64);
  quantum_k<<<dim3(4096), blk, 0, stream>>>(ZP, GATES, QOUT);
  gemm_k<<<dim3(64,2), blk, 0, stream>>>(QOUT, Wq1, bq1, BUF2, 128, 18);
  colstats_k<<<dim3(2,16), blk, 0, stream>>>(BUF2, SQ1, 128);
  bn_k<<<dim3(4096*128/256), blk, 0, stream>>>(BUF2, SQ1, gq1, beq1, SKIP, 1.0f, 128, BUF2, 128);
  gemm_k<<<dim3(64,1), blk, 0, stream>>>(BUF2, Wq2, bq2, BUF3, 64, 128);
  colstats_k<<<dim3(1,16), blk, 0, stream>>>(BUF3, SQ2, 64);
  bn_k<<<dim3(4096*64/256), blk, 0, stream>>>(BUF3, SQ2, gq2, beq2, nullptr, 0.f, 0, BUF3, 64);
  final_k<<<dim3(512), blk, 0, stream>>>(BUF3, Wo1, bo1, Wo2, bo2, out);
}